// Round 1
// baseline (1215.909 us; speedup 1.0000x reference)
//
#include <hip/hip_runtime.h>
#include <cstdint>
#include <cstddef>

#define NN 100000      // nodes
#define NE 1600000     // edges
#define HID 100
#define INF 16

__device__ __forceinline__ void fma4(float4& a, float s, const float4 w) {
  a.x += s * w.x; a.y += s * w.y; a.z += s * w.z; a.w += s * w.w;
}

// ---------------- CSR build ----------------
__global__ void k_hist(const int* __restrict__ dst, int* __restrict__ deg) {
  int e = blockIdx.x * 256 + threadIdx.x;
  if (e < NE) atomicAdd(&deg[dst[e]], 1);
}

// per-block exclusive scan of deg -> offs, block totals -> bsum
__global__ void k_scan1(const int* __restrict__ deg, int* __restrict__ offs,
                        int* __restrict__ bsum) {
  __shared__ int s[256];
  int t = threadIdx.x;
  int i = blockIdx.x * 256 + t;
  int v = (i < NN) ? deg[i] : 0;
  s[t] = v; __syncthreads();
  for (int off = 1; off < 256; off <<= 1) {
    int x = (t >= off) ? s[t - off] : 0;
    __syncthreads();
    s[t] += x;
    __syncthreads();
  }
  if (i < NN) offs[i] = s[t] - v;          // exclusive within block
  if (t == 255) bsum[blockIdx.x] = s[255]; // block total
}

__global__ void k_scan2(int* __restrict__ bsum, int nb) {
  __shared__ int s[512];
  int t = threadIdx.x;
  int v = (t < nb) ? bsum[t] : 0;
  s[t] = v; __syncthreads();
  for (int off = 1; off < 512; off <<= 1) {
    int x = (t >= off) ? s[t - off] : 0;
    __syncthreads();
    s[t] += x;
    __syncthreads();
  }
  if (t < nb) bsum[t] = s[t] - v;          // exclusive
}

__global__ void k_scan3(int* __restrict__ offs, const int* __restrict__ bsum) {
  int i = blockIdx.x * 256 + threadIdx.x;
  if (i < NN) offs[i] += bsum[i >> 8];
  else if (i == NN) offs[NN] = NE;
}

__global__ void k_fill(const int* __restrict__ src, const int* __restrict__ dst,
                       const float* __restrict__ ef, int* __restrict__ cursor,
                       int* __restrict__ ssrc, float* __restrict__ sw) {
  int e = blockIdx.x * 256 + threadIdx.x;
  if (e >= NE) return;
  int d = dst[e];
  int p = atomicAdd(&cursor[d], 1);
  ssrc[p] = src[e];
  sw[p] = ef[e];
}

// ---------------- lift: h = tanh(x @ Wl + bl), thread per node ----------------
__global__ __launch_bounds__(256) void k_lift(const float* __restrict__ x,
                                              const float* __restrict__ Wl,
                                              const float* __restrict__ bl,
                                              float* __restrict__ h) {
  int n = blockIdx.x * 256 + threadIdx.x;
  if (n >= NN) return;
  const float4* W4 = (const float4*)Wl;        // [16][25] float4
  const float4* b4 = (const float4*)bl;
  float4 acc[25];
  #pragma unroll
  for (int j = 0; j < 25; ++j) acc[j] = b4[j];
  const float4* xr = (const float4*)(x + (size_t)n * INF);
  for (int k4 = 0; k4 < 4; ++k4) {
    float4 xv = xr[k4];
    #pragma unroll
    for (int c = 0; c < 4; ++c) {
      float xs = (&xv.x)[c];
      int k = k4 * 4 + c;
      #pragma unroll
      for (int j = 0; j < 25; ++j) fma4(acc[j], xs, W4[k * 25 + j]);
    }
  }
  float4* o = (float4*)(h + (size_t)n * HID);
  #pragma unroll
  for (int j = 0; j < 25; ++j) {
    float4 v = acc[j];
    v.x = tanhf(v.x); v.y = tanhf(v.y); v.z = tanhf(v.z); v.w = tanhf(v.w);
    o[j] = v;
  }
}

// -------- reduce: red[n][f] = sum over in-edges of h[src][f]*w; wave per node --------
__global__ __launch_bounds__(256) void k_reduce(const float* __restrict__ h,
                                                const int* __restrict__ offs,
                                                const int* __restrict__ ssrc,
                                                const float* __restrict__ sw,
                                                float* __restrict__ red) {
  int wid = (blockIdx.x * 256 + threadIdx.x) >> 6;  // node
  int lane = threadIdx.x & 63;
  if (wid >= NN) return;
  int beg = offs[wid], end = offs[wid + 1];
  float acc0 = 0.f, acc1 = 0.f;
  const int f1 = 64 + lane;                         // lanes 0..35 cover 64..99
  for (int i = beg; i < end; ++i) {
    int s = ssrc[i];            // same addr across wave -> broadcast
    float w = sw[i];
    const float* hr = h + (size_t)s * HID;
    acc0 += hr[lane] * w;
    if (f1 < HID) acc1 += hr[f1] * w;
  }
  float* rr = red + (size_t)wid * HID;
  rr[lane] = acc0;
  if (f1 < HID) rr[f1] = acc1;
}

// -------- mlp: out = relu(h @ W[0:100] + r @ W[100:200] + b), thread per node --------
// out may alias r (each thread reads its own row fully before writing it).
__global__ __launch_bounds__(256) void k_mlp(const float* __restrict__ h,
                                             const float* r,
                                             const float* __restrict__ W,
                                             const float* __restrict__ b,
                                             float* out) {
  int n = blockIdx.x * 256 + threadIdx.x;
  if (n >= NN) return;
  const float4* W4a = (const float4*)W;                 // rows 0..99,  [k][25]
  const float4* W4b = (const float4*)(W + HID * HID);   // rows 100..199
  const float4* b4 = (const float4*)b;
  float4 acc[25];
  #pragma unroll
  for (int j = 0; j < 25; ++j) acc[j] = b4[j];

  const float4* hr = (const float4*)(h + (size_t)n * HID);
  for (int k4 = 0; k4 < 25; ++k4) {
    float4 hv = hr[k4];
    #pragma unroll
    for (int c = 0; c < 4; ++c) {
      float xs = (&hv.x)[c];
      int k = k4 * 4 + c;
      #pragma unroll
      for (int j = 0; j < 25; ++j) fma4(acc[j], xs, W4a[k * 25 + j]);
    }
  }
  const float4* rr = (const float4*)(r + (size_t)n * HID);
  for (int k4 = 0; k4 < 25; ++k4) {
    float4 hv = rr[k4];
    #pragma unroll
    for (int c = 0; c < 4; ++c) {
      float xs = (&hv.x)[c];
      int k = k4 * 4 + c;
      #pragma unroll
      for (int j = 0; j < 25; ++j) fma4(acc[j], xs, W4b[k * 25 + j]);
    }
  }
  float4* o = (float4*)(out + (size_t)n * HID);
  #pragma unroll
  for (int j = 0; j < 25; ++j) {
    float4 v = acc[j];
    v.x = fmaxf(v.x, 0.f); v.y = fmaxf(v.y, 0.f);
    v.z = fmaxf(v.z, 0.f); v.w = fmaxf(v.w, 0.f);
    o[j] = v;
  }
}

// -------- out: sigmoid(h @ Wo + bo), thread per node --------
__global__ __launch_bounds__(256) void k_out(const float* __restrict__ h,
                                             const float* __restrict__ Wo,
                                             const float* __restrict__ bo,
                                             float* __restrict__ out) {
  int n = blockIdx.x * 256 + threadIdx.x;
  if (n >= NN) return;
  float a0 = bo[0], a1 = bo[1], a2 = bo[2];
  const float4* hr = (const float4*)(h + (size_t)n * HID);
  for (int k4 = 0; k4 < 25; ++k4) {
    float4 hv = hr[k4];
    #pragma unroll
    for (int c = 0; c < 4; ++c) {
      int k = k4 * 4 + c;
      float xs = (&hv.x)[c];
      a0 += xs * Wo[k * 3 + 0];
      a1 += xs * Wo[k * 3 + 1];
      a2 += xs * Wo[k * 3 + 2];
    }
  }
  out[(size_t)n * 3 + 0] = 1.f / (1.f + expf(-a0));
  out[(size_t)n * 3 + 1] = 1.f / (1.f + expf(-a1));
  out[(size_t)n * 3 + 2] = 1.f / (1.f + expf(-a2));
}

extern "C" void kernel_launch(void* const* d_in, const int* in_sizes, int n_in,
                              void* d_out, int out_size, void* d_ws, size_t ws_size,
                              hipStream_t stream) {
  const float* x  = (const float*)d_in[0];
  const float* ef = (const float*)d_in[1];
  const int*   src = (const int*)d_in[2];
  const int*   dst = (const int*)d_in[3];
  const float* Wl = (const float*)d_in[4];
  const float* bl = (const float*)d_in[5];
  const float* W1 = (const float*)d_in[6];
  const float* b1 = (const float*)d_in[7];
  const float* W2 = (const float*)d_in[8];
  const float* b2 = (const float*)d_in[9];
  const float* W3 = (const float*)d_in[10];
  const float* b3 = (const float*)d_in[11];
  const float* Wo = (const float*)d_in[12];
  const float* bo = (const float*)d_in[13];
  float* out = (float*)d_out;

  // workspace layout (~93.6 MB)
  char* ws = (char*)d_ws;
  float* hA    = (float*)(ws);                      // 40,000,000 B
  float* hB    = (float*)(ws + 40000000);           // 40,000,000 B
  int*   offs  = (int*)  (ws + 80000000);           // (NN+1)*4 -> pad 400,128
  int*   cursor= (int*)  (ws + 80400128);           // NN*4 -> pad 400,128 (also deg)
  int*   ssrc  = (int*)  (ws + 80800256);           // NE*4
  float* swt   = (float*)(ws + 87200256);           // NE*4
  int*   bsum  = (int*)  (ws + 93600256);           // 391*4

  const int scanBlocks = (NN + 255) / 256;          // 391

  // ---- CSR build (deg lives in `cursor`) ----
  hipMemsetAsync(cursor, 0, NN * sizeof(int), stream);
  k_hist <<<(NE + 255) / 256, 256, 0, stream>>>(dst, cursor);
  k_scan1<<<scanBlocks, 256, 0, stream>>>(cursor, offs, bsum);
  k_scan2<<<1, 512, 0, stream>>>(bsum, scanBlocks);
  k_scan3<<<scanBlocks, 256, 0, stream>>>(offs, bsum);
  hipMemcpyAsync(cursor, offs, NN * sizeof(int), hipMemcpyDeviceToDevice, stream);
  k_fill <<<(NE + 255) / 256, 256, 0, stream>>>(src, dst, ef, cursor, ssrc, swt);

  // ---- network ----
  k_lift<<<scanBlocks, 256, 0, stream>>>(x, Wl, bl, hA);

  k_reduce<<<NN / 4, 256, 0, stream>>>(hA, offs, ssrc, swt, hB);
  k_mlp   <<<scanBlocks, 256, 0, stream>>>(hA, hB, W1, b1, hB);

  k_reduce<<<NN / 4, 256, 0, stream>>>(hB, offs, ssrc, swt, hA);
  k_mlp   <<<scanBlocks, 256, 0, stream>>>(hB, hA, W2, b2, hA);

  k_reduce<<<NN / 4, 256, 0, stream>>>(hA, offs, ssrc, swt, hB);
  k_mlp   <<<scanBlocks, 256, 0, stream>>>(hA, hB, W3, b3, hB);

  k_out<<<scanBlocks, 256, 0, stream>>>(hB, Wo, bo, out);
}

// Round 2
// 1032.193 us; speedup vs baseline: 1.1780x; 1.1780x over previous
//
#include <hip/hip_runtime.h>
#include <cstdint>
#include <cstddef>

#define NN 100000      // nodes
#define NE 1600000     // edges
#define HID 100
#define INF 16

__device__ __forceinline__ void fma4(float4& a, float s, const float4 w) {
  a.x += s * w.x; a.y += s * w.y; a.z += s * w.z; a.w += s * w.w;
}

// ---------------- CSR build ----------------
__global__ void k_hist(const int* __restrict__ dst, int* __restrict__ deg) {
  int e = blockIdx.x * 256 + threadIdx.x;
  if (e < NE) atomicAdd(&deg[dst[e]], 1);
}

// per-block exclusive scan of deg -> offs, block totals -> bsum
__global__ void k_scan1(const int* __restrict__ deg, int* __restrict__ offs,
                        int* __restrict__ bsum) {
  __shared__ int s[256];
  int t = threadIdx.x;
  int i = blockIdx.x * 256 + t;
  int v = (i < NN) ? deg[i] : 0;
  s[t] = v; __syncthreads();
  for (int off = 1; off < 256; off <<= 1) {
    int x = (t >= off) ? s[t - off] : 0;
    __syncthreads();
    s[t] += x;
    __syncthreads();
  }
  if (i < NN) offs[i] = s[t] - v;          // exclusive within block
  if (t == 255) bsum[blockIdx.x] = s[255]; // block total
}

__global__ void k_scan2(int* __restrict__ bsum, int nb) {
  __shared__ int s[512];
  int t = threadIdx.x;
  int v = (t < nb) ? bsum[t] : 0;
  s[t] = v; __syncthreads();
  for (int off = 1; off < 512; off <<= 1) {
    int x = (t >= off) ? s[t - off] : 0;
    __syncthreads();
    s[t] += x;
    __syncthreads();
  }
  if (t < nb) bsum[t] = s[t] - v;          // exclusive
}

__global__ void k_scan3(int* __restrict__ offs, const int* __restrict__ bsum) {
  int i = blockIdx.x * 256 + threadIdx.x;
  if (i < NN) offs[i] += bsum[i >> 8];
  else if (i == NN) offs[NN] = NE;
}

__global__ void k_fill(const int* __restrict__ src, const int* __restrict__ dst,
                       const float* __restrict__ ef, int* __restrict__ cursor,
                       int* __restrict__ ssrc, float* __restrict__ sw) {
  int e = blockIdx.x * 256 + threadIdx.x;
  if (e >= NE) return;
  int d = dst[e];
  int p = atomicAdd(&cursor[d], 1);
  ssrc[p] = src[e];
  sw[p] = ef[e];
}

// ---------------- lift: h = tanh(x @ Wl + bl), thread per node ----------------
__global__ __launch_bounds__(256) void k_lift(const float* __restrict__ x,
                                              const float* __restrict__ Wl,
                                              const float* __restrict__ bl,
                                              float* __restrict__ h) {
  int n = blockIdx.x * 256 + threadIdx.x;
  if (n >= NN) return;
  const float4* W4 = (const float4*)Wl;        // [16][25] float4
  const float4* b4 = (const float4*)bl;
  float4 acc[25];
  #pragma unroll
  for (int j = 0; j < 25; ++j) acc[j] = b4[j];
  const float4* xr = (const float4*)(x + (size_t)n * INF);
  for (int k4 = 0; k4 < 4; ++k4) {
    float4 xv = xr[k4];
    #pragma unroll
    for (int c = 0; c < 4; ++c) {
      float xs = (&xv.x)[c];
      int k = k4 * 4 + c;
      #pragma unroll
      for (int j = 0; j < 25; ++j) fma4(acc[j], xs, W4[k * 25 + j]);
    }
  }
  float4* o = (float4*)(h + (size_t)n * HID);
  #pragma unroll
  for (int j = 0; j < 25; ++j) {
    float4 v = acc[j];
    v.x = tanhf(v.x); v.y = tanhf(v.y); v.z = tanhf(v.z); v.w = tanhf(v.w);
    o[j] = v;
  }
}

// -------- reduce: red[n][f] = sum over in-edges of h[src][f]*w --------
// wave per node; lanes 0..24 each own a float4 (4 features); edge loop
// unrolled x4 with independent dwordx4 gathers in flight; ssrc/sw loads are
// wave-uniform (node id via readfirstlane) -> scalar pipe.
__global__ __launch_bounds__(256) void k_reduce(const float* __restrict__ h,
                                                const int* __restrict__ offs,
                                                const int* __restrict__ ssrc,
                                                const float* __restrict__ sw,
                                                float* __restrict__ red) {
  int wid = (blockIdx.x * 256 + threadIdx.x) >> 6;  // node (grid exact: 100k waves)
  int node = __builtin_amdgcn_readfirstlane(wid);
  int lane = threadIdx.x & 63;
  int lc = lane < 25 ? lane : 24;   // clamp: lanes 25..63 dup lane 24's line
  int beg = offs[node], end = offs[node + 1];
  const float4* __restrict__ h4 = (const float4*)h;
  float4 acc = make_float4(0.f, 0.f, 0.f, 0.f);
  int i = beg;
  for (; i + 4 <= end; i += 4) {
    int s0 = ssrc[i + 0], s1 = ssrc[i + 1], s2 = ssrc[i + 2], s3 = ssrc[i + 3];
    float w0 = sw[i + 0], w1 = sw[i + 1], w2 = sw[i + 2], w3 = sw[i + 3];
    float4 v0 = h4[(size_t)s0 * 25 + lc];
    float4 v1 = h4[(size_t)s1 * 25 + lc];
    float4 v2 = h4[(size_t)s2 * 25 + lc];
    float4 v3 = h4[(size_t)s3 * 25 + lc];
    fma4(acc, w0, v0);
    fma4(acc, w1, v1);
    fma4(acc, w2, v2);
    fma4(acc, w3, v3);
  }
  for (; i < end; ++i) {
    int s = ssrc[i];
    float w = sw[i];
    float4 v = h4[(size_t)s * 25 + lc];
    fma4(acc, w, v);
  }
  if (lane < 25) ((float4*)red)[(size_t)node * 25 + lane] = acc;
}

// -------- mlp: out = relu(h @ W[0:100] + r @ W[100:200] + b), thread per node --------
// out may alias r (each thread reads its own row fully before writing it).
__global__ __launch_bounds__(256) void k_mlp(const float* __restrict__ h,
                                             const float* r,
                                             const float* __restrict__ W,
                                             const float* __restrict__ b,
                                             float* out) {
  int n = blockIdx.x * 256 + threadIdx.x;
  if (n >= NN) return;
  const float4* W4a = (const float4*)W;                 // rows 0..99,  [k][25]
  const float4* W4b = (const float4*)(W + HID * HID);   // rows 100..199
  const float4* b4 = (const float4*)b;
  float4 acc[25];
  #pragma unroll
  for (int j = 0; j < 25; ++j) acc[j] = b4[j];

  const float4* hr = (const float4*)(h + (size_t)n * HID);
  for (int k4 = 0; k4 < 25; ++k4) {
    float4 hv = hr[k4];
    #pragma unroll
    for (int c = 0; c < 4; ++c) {
      float xs = (&hv.x)[c];
      int k = k4 * 4 + c;
      #pragma unroll
      for (int j = 0; j < 25; ++j) fma4(acc[j], xs, W4a[k * 25 + j]);
    }
  }
  const float4* rr = (const float4*)(r + (size_t)n * HID);
  for (int k4 = 0; k4 < 25; ++k4) {
    float4 hv = rr[k4];
    #pragma unroll
    for (int c = 0; c < 4; ++c) {
      float xs = (&hv.x)[c];
      int k = k4 * 4 + c;
      #pragma unroll
      for (int j = 0; j < 25; ++j) fma4(acc[j], xs, W4b[k * 25 + j]);
    }
  }
  float4* o = (float4*)(out + (size_t)n * HID);
  #pragma unroll
  for (int j = 0; j < 25; ++j) {
    float4 v = acc[j];
    v.x = fmaxf(v.x, 0.f); v.y = fmaxf(v.y, 0.f);
    v.z = fmaxf(v.z, 0.f); v.w = fmaxf(v.w, 0.f);
    o[j] = v;
  }
}

// -------- out: sigmoid(h @ Wo + bo), thread per node --------
__global__ __launch_bounds__(256) void k_out(const float* __restrict__ h,
                                             const float* __restrict__ Wo,
                                             const float* __restrict__ bo,
                                             float* __restrict__ out) {
  int n = blockIdx.x * 256 + threadIdx.x;
  if (n >= NN) return;
  float a0 = bo[0], a1 = bo[1], a2 = bo[2];
  const float4* hr = (const float4*)(h + (size_t)n * HID);
  for (int k4 = 0; k4 < 25; ++k4) {
    float4 hv = hr[k4];
    #pragma unroll
    for (int c = 0; c < 4; ++c) {
      int k = k4 * 4 + c;
      float xs = (&hv.x)[c];
      a0 += xs * Wo[k * 3 + 0];
      a1 += xs * Wo[k * 3 + 1];
      a2 += xs * Wo[k * 3 + 2];
    }
  }
  out[(size_t)n * 3 + 0] = 1.f / (1.f + expf(-a0));
  out[(size_t)n * 3 + 1] = 1.f / (1.f + expf(-a1));
  out[(size_t)n * 3 + 2] = 1.f / (1.f + expf(-a2));
}

extern "C" void kernel_launch(void* const* d_in, const int* in_sizes, int n_in,
                              void* d_out, int out_size, void* d_ws, size_t ws_size,
                              hipStream_t stream) {
  const float* x  = (const float*)d_in[0];
  const float* ef = (const float*)d_in[1];
  const int*   src = (const int*)d_in[2];
  const int*   dst = (const int*)d_in[3];
  const float* Wl = (const float*)d_in[4];
  const float* bl = (const float*)d_in[5];
  const float* W1 = (const float*)d_in[6];
  const float* b1 = (const float*)d_in[7];
  const float* W2 = (const float*)d_in[8];
  const float* b2 = (const float*)d_in[9];
  const float* W3 = (const float*)d_in[10];
  const float* b3 = (const float*)d_in[11];
  const float* Wo = (const float*)d_in[12];
  const float* bo = (const float*)d_in[13];
  float* out = (float*)d_out;

  // workspace layout (~93.6 MB)
  char* ws = (char*)d_ws;
  float* hA    = (float*)(ws);                      // 40,000,000 B
  float* hB    = (float*)(ws + 40000000);           // 40,000,000 B
  int*   offs  = (int*)  (ws + 80000000);           // (NN+1)*4 -> pad 400,128
  int*   cursor= (int*)  (ws + 80400128);           // NN*4 -> pad 400,128 (also deg)
  int*   ssrc  = (int*)  (ws + 80800256);           // NE*4
  float* swt   = (float*)(ws + 87200256);           // NE*4
  int*   bsum  = (int*)  (ws + 93600256);           // 391*4

  const int scanBlocks = (NN + 255) / 256;          // 391

  // ---- CSR build (deg lives in `cursor`) ----
  hipMemsetAsync(cursor, 0, NN * sizeof(int), stream);
  k_hist <<<(NE + 255) / 256, 256, 0, stream>>>(dst, cursor);
  k_scan1<<<scanBlocks, 256, 0, stream>>>(cursor, offs, bsum);
  k_scan2<<<1, 512, 0, stream>>>(bsum, scanBlocks);
  k_scan3<<<scanBlocks, 256, 0, stream>>>(offs, bsum);
  hipMemcpyAsync(cursor, offs, NN * sizeof(int), hipMemcpyDeviceToDevice, stream);
  k_fill <<<(NE + 255) / 256, 256, 0, stream>>>(src, dst, ef, cursor, ssrc, swt);

  // ---- network ----
  k_lift<<<scanBlocks, 256, 0, stream>>>(x, Wl, bl, hA);

  k_reduce<<<NN / 4, 256, 0, stream>>>(hA, offs, ssrc, swt, hB);
  k_mlp   <<<scanBlocks, 256, 0, stream>>>(hA, hB, W1, b1, hB);

  k_reduce<<<NN / 4, 256, 0, stream>>>(hB, offs, ssrc, swt, hA);
  k_mlp   <<<scanBlocks, 256, 0, stream>>>(hB, hA, W2, b2, hA);

  k_reduce<<<NN / 4, 256, 0, stream>>>(hA, offs, ssrc, swt, hB);
  k_mlp   <<<scanBlocks, 256, 0, stream>>>(hA, hB, W3, b3, hB);

  k_out<<<scanBlocks, 256, 0, stream>>>(hB, Wo, bo, out);
}

// Round 3
// 921.639 us; speedup vs baseline: 1.3193x; 1.1200x over previous
//
#include <hip/hip_runtime.h>
#include <cstdint>
#include <cstddef>

#define NN 100000      // nodes
#define NE 1600000     // edges
#define HID 100
#define INF 16

__device__ __forceinline__ void fma4(float4& a, float s, const float4 w) {
  a.x += s * w.x; a.y += s * w.y; a.z += s * w.z; a.w += s * w.w;
}

// ---------------- CSR build ----------------
__global__ void k_hist(const int* __restrict__ dst, int* __restrict__ deg) {
  int e = blockIdx.x * 256 + threadIdx.x;
  if (e < NE) atomicAdd(&deg[dst[e]], 1);
}

// per-block exclusive scan of deg -> offs, block totals -> bsum
__global__ void k_scan1(const int* __restrict__ deg, int* __restrict__ offs,
                        int* __restrict__ bsum) {
  __shared__ int s[256];
  int t = threadIdx.x;
  int i = blockIdx.x * 256 + t;
  int v = (i < NN) ? deg[i] : 0;
  s[t] = v; __syncthreads();
  for (int off = 1; off < 256; off <<= 1) {
    int x = (t >= off) ? s[t - off] : 0;
    __syncthreads();
    s[t] += x;
    __syncthreads();
  }
  if (i < NN) offs[i] = s[t] - v;          // exclusive within block
  if (t == 255) bsum[blockIdx.x] = s[255]; // block total
}

__global__ void k_scan2(int* __restrict__ bsum, int nb) {
  __shared__ int s[512];
  int t = threadIdx.x;
  int v = (t < nb) ? bsum[t] : 0;
  s[t] = v; __syncthreads();
  for (int off = 1; off < 512; off <<= 1) {
    int x = (t >= off) ? s[t - off] : 0;
    __syncthreads();
    s[t] += x;
    __syncthreads();
  }
  if (t < nb) bsum[t] = s[t] - v;          // exclusive
}

__global__ void k_scan3(int* __restrict__ offs, const int* __restrict__ bsum) {
  int i = blockIdx.x * 256 + threadIdx.x;
  if (i < NN) offs[i] += bsum[i >> 8];
  else if (i == NN) offs[NN] = NE;
}

__global__ void k_fill(const int* __restrict__ src, const int* __restrict__ dst,
                       const float* __restrict__ ef, int* __restrict__ cursor,
                       int* __restrict__ ssrc, float* __restrict__ sw) {
  int e = blockIdx.x * 256 + threadIdx.x;
  if (e >= NE) return;
  int d = dst[e];
  int p = atomicAdd(&cursor[d], 1);
  ssrc[p] = src[e];
  sw[p] = ef[e];
}

// ---------------- lift: h = tanh(x @ Wl + bl), thread per node ----------------
__global__ __launch_bounds__(256) void k_lift(const float* __restrict__ x,
                                              const float* __restrict__ Wl,
                                              const float* __restrict__ bl,
                                              float* __restrict__ h) {
  int n = blockIdx.x * 256 + threadIdx.x;
  if (n >= NN) return;
  const float4* W4 = (const float4*)Wl;        // [16][25] float4
  const float4* b4 = (const float4*)bl;
  float4 acc[25];
  #pragma unroll
  for (int j = 0; j < 25; ++j) acc[j] = b4[j];
  const float4* xr = (const float4*)(x + (size_t)n * INF);
  for (int k4 = 0; k4 < 4; ++k4) {
    float4 xv = xr[k4];
    #pragma unroll
    for (int c = 0; c < 4; ++c) {
      float xs = (&xv.x)[c];
      int k = k4 * 4 + c;
      #pragma unroll
      for (int j = 0; j < 25; ++j) fma4(acc[j], xs, W4[k * 25 + j]);
    }
  }
  float4* o = (float4*)(h + (size_t)n * HID);
  #pragma unroll
  for (int j = 0; j < 25; ++j) {
    float4 v = acc[j];
    v.x = tanhf(v.x); v.y = tanhf(v.y); v.z = tanhf(v.z); v.w = tanhf(v.w);
    o[j] = v;
  }
}

// -------- reduce: red[n][f] = sum over in-edges of h[src][f]*w --------
// wave per node; lanes 0..24 each own a float4 (4 features); edge loop
// unrolled x4 with independent dwordx4 gathers in flight.
__global__ __launch_bounds__(256) void k_reduce(const float* __restrict__ h,
                                                const int* __restrict__ offs,
                                                const int* __restrict__ ssrc,
                                                const float* __restrict__ sw,
                                                float* __restrict__ red) {
  int wid = (blockIdx.x * 256 + threadIdx.x) >> 6;  // node (grid exact: 100k waves)
  int node = __builtin_amdgcn_readfirstlane(wid);
  int lane = threadIdx.x & 63;
  int lc = lane < 25 ? lane : 24;   // clamp: lanes 25..63 dup lane 24's line
  int beg = offs[node], end = offs[node + 1];
  const float4* __restrict__ h4 = (const float4*)h;
  float4 acc = make_float4(0.f, 0.f, 0.f, 0.f);
  int i = beg;
  for (; i + 4 <= end; i += 4) {
    int s0 = ssrc[i + 0], s1 = ssrc[i + 1], s2 = ssrc[i + 2], s3 = ssrc[i + 3];
    float w0 = sw[i + 0], w1 = sw[i + 1], w2 = sw[i + 2], w3 = sw[i + 3];
    float4 v0 = h4[(size_t)s0 * 25 + lc];
    float4 v1 = h4[(size_t)s1 * 25 + lc];
    float4 v2 = h4[(size_t)s2 * 25 + lc];
    float4 v3 = h4[(size_t)s3 * 25 + lc];
    fma4(acc, w0, v0);
    fma4(acc, w1, v1);
    fma4(acc, w2, v2);
    fma4(acc, w3, v3);
  }
  for (; i < end; ++i) {
    int s = ssrc[i];
    float w = sw[i];
    float4 v = h4[(size_t)s * 25 + lc];
    fma4(acc, w, v);
  }
  if (lane < 25) ((float4*)red)[(size_t)node * 25 + lane] = acc;
}

// -------- mlp: out = relu(h @ W[0:100] + r @ W[100:200] + b) --------
// Block = 256 threads = 4 waves = 64 nodes. Wave w computes output columns
// [25w, 25w+25) for all 64 nodes: acc[25] scalars per thread. Node rows are
// staged in LDS (stride 101 -> conflict-free); the 25 W values per k are
// wave-uniform (w forced uniform) -> scalar loads on the s-pipe.
// out may alias r: each block stages its own r rows before storing its own
// out rows; no cross-block overlap.
__global__ __launch_bounds__(256) void k_mlp(const float* __restrict__ h,
                                             const float* r,
                                             const float* __restrict__ W,
                                             const float* __restrict__ b,
                                             float* out) {
  __shared__ float sh[64][101];
  const int t = threadIdx.x;
  const int w = __builtin_amdgcn_readfirstlane(t >> 6);  // wave id 0..3
  const int lane = t & 63;
  const size_t base = (size_t)blockIdx.x * 6400;
  const size_t limit = (size_t)NN * HID;
  const float* Wq = W + w * 25;

  float acc[25];
  #pragma unroll
  for (int j = 0; j < 25; ++j) acc[j] = b[w * 25 + j];

  // ---- phase 1: stage h rows, accumulate vs W rows 0..99 ----
  #pragma unroll
  for (int i = 0; i < 25; ++i) {
    int flat = i * 256 + t;
    size_t g = base + flat;
    if (g >= limit) g = limit - 1;
    sh[flat / 100][flat % 100] = h[g];
  }
  __syncthreads();
  #pragma unroll 2
  for (int k = 0; k < 100; ++k) {
    float hv = sh[lane][k];
    const float* Wrow = Wq + (size_t)k * HID;
    #pragma unroll
    for (int j = 0; j < 25; ++j) acc[j] = fmaf(hv, Wrow[j], acc[j]);
  }
  __syncthreads();

  // ---- phase 2: stage r rows, accumulate vs W rows 100..199 ----
  #pragma unroll
  for (int i = 0; i < 25; ++i) {
    int flat = i * 256 + t;
    size_t g = base + flat;
    if (g >= limit) g = limit - 1;
    sh[flat / 100][flat % 100] = r[g];
  }
  __syncthreads();
  #pragma unroll 2
  for (int k = 0; k < 100; ++k) {
    float hv = sh[lane][k];
    const float* Wrow = Wq + (size_t)(HID + k) * HID;
    #pragma unroll
    for (int j = 0; j < 25; ++j) acc[j] = fmaf(hv, Wrow[j], acc[j]);
  }
  __syncthreads();

  // ---- relu + transpose through LDS for coalesced store ----
  #pragma unroll
  for (int j = 0; j < 25; ++j) sh[lane][w * 25 + j] = fmaxf(acc[j], 0.f);
  __syncthreads();
  #pragma unroll
  for (int i = 0; i < 25; ++i) {
    int flat = i * 256 + t;
    size_t g = base + flat;
    if (g < limit) out[g] = sh[flat / 100][flat % 100];
  }
}

// -------- out: sigmoid(h @ Wo + bo), thread per node --------
__global__ __launch_bounds__(256) void k_out(const float* __restrict__ h,
                                             const float* __restrict__ Wo,
                                             const float* __restrict__ bo,
                                             float* __restrict__ out) {
  int n = blockIdx.x * 256 + threadIdx.x;
  if (n >= NN) return;
  float a0 = bo[0], a1 = bo[1], a2 = bo[2];
  const float4* hr = (const float4*)(h + (size_t)n * HID);
  for (int k4 = 0; k4 < 25; ++k4) {
    float4 hv = hr[k4];
    #pragma unroll
    for (int c = 0; c < 4; ++c) {
      int k = k4 * 4 + c;
      float xs = (&hv.x)[c];
      a0 += xs * Wo[k * 3 + 0];
      a1 += xs * Wo[k * 3 + 1];
      a2 += xs * Wo[k * 3 + 2];
    }
  }
  out[(size_t)n * 3 + 0] = 1.f / (1.f + expf(-a0));
  out[(size_t)n * 3 + 1] = 1.f / (1.f + expf(-a1));
  out[(size_t)n * 3 + 2] = 1.f / (1.f + expf(-a2));
}

extern "C" void kernel_launch(void* const* d_in, const int* in_sizes, int n_in,
                              void* d_out, int out_size, void* d_ws, size_t ws_size,
                              hipStream_t stream) {
  const float* x  = (const float*)d_in[0];
  const float* ef = (const float*)d_in[1];
  const int*   src = (const int*)d_in[2];
  const int*   dst = (const int*)d_in[3];
  const float* Wl = (const float*)d_in[4];
  const float* bl = (const float*)d_in[5];
  const float* W1 = (const float*)d_in[6];
  const float* b1 = (const float*)d_in[7];
  const float* W2 = (const float*)d_in[8];
  const float* b2 = (const float*)d_in[9];
  const float* W3 = (const float*)d_in[10];
  const float* b3 = (const float*)d_in[11];
  const float* Wo = (const float*)d_in[12];
  const float* bo = (const float*)d_in[13];
  float* out = (float*)d_out;

  // workspace layout (~93.6 MB)
  char* ws = (char*)d_ws;
  float* hA    = (float*)(ws);                      // 40,000,000 B
  float* hB    = (float*)(ws + 40000000);           // 40,000,000 B
  int*   offs  = (int*)  (ws + 80000000);           // (NN+1)*4 -> pad 400,128
  int*   cursor= (int*)  (ws + 80400128);           // NN*4 -> pad 400,128 (also deg)
  int*   ssrc  = (int*)  (ws + 80800256);           // NE*4
  float* swt   = (float*)(ws + 87200256);           // NE*4
  int*   bsum  = (int*)  (ws + 93600256);           // 391*4

  const int scanBlocks = (NN + 255) / 256;          // 391
  const int mlpBlocks  = (NN + 63) / 64;            // 1563

  // ---- CSR build (deg lives in `cursor`) ----
  hipMemsetAsync(cursor, 0, NN * sizeof(int), stream);
  k_hist <<<(NE + 255) / 256, 256, 0, stream>>>(dst, cursor);
  k_scan1<<<scanBlocks, 256, 0, stream>>>(cursor, offs, bsum);
  k_scan2<<<1, 512, 0, stream>>>(bsum, scanBlocks);
  k_scan3<<<scanBlocks, 256, 0, stream>>>(offs, bsum);
  hipMemcpyAsync(cursor, offs, NN * sizeof(int), hipMemcpyDeviceToDevice, stream);
  k_fill <<<(NE + 255) / 256, 256, 0, stream>>>(src, dst, ef, cursor, ssrc, swt);

  // ---- network ----
  k_lift<<<scanBlocks, 256, 0, stream>>>(x, Wl, bl, hA);

  k_reduce<<<NN / 4, 256, 0, stream>>>(hA, offs, ssrc, swt, hB);
  k_mlp   <<<mlpBlocks, 256, 0, stream>>>(hA, hB, W1, b1, hB);

  k_reduce<<<NN / 4, 256, 0, stream>>>(hB, offs, ssrc, swt, hA);
  k_mlp   <<<mlpBlocks, 256, 0, stream>>>(hB, hA, W2, b2, hA);

  k_reduce<<<NN / 4, 256, 0, stream>>>(hA, offs, ssrc, swt, hB);
  k_mlp   <<<mlpBlocks, 256, 0, stream>>>(hA, hB, W3, b3, hB);

  k_out<<<scanBlocks, 256, 0, stream>>>(hB, Wo, bo, out);
}

// Round 5
// 720.032 us; speedup vs baseline: 1.6887x; 1.2800x over previous
//
#include <hip/hip_runtime.h>
#include <hip/hip_fp16.h>
#include <cstdint>
#include <cstddef>

#define NN 100000      // nodes
#define NE 1600000     // edges
#define HID 100
#define INF 16

// ---- fp16 helpers (h is stored fp16; all math fp32) ----
__device__ __forceinline__ float2 up_f16(unsigned int u) {   // unpack 2 halves
  __half2 h = *reinterpret_cast<const __half2*>(&u);
  return __half22float2(h);
}
__device__ __forceinline__ unsigned int pk_f16(float lo, float hi) {  // RNE pack
  __half2 h = __floats2half2_rn(lo, hi);
  return *reinterpret_cast<const unsigned int*>(&h);
}

// ---------------- CSR build ----------------
__global__ void k_hist(const int* __restrict__ dst, int* __restrict__ deg) {
  int e = blockIdx.x * 256 + threadIdx.x;
  if (e < NE) atomicAdd(&deg[dst[e]], 1);
}

__global__ void k_scan1(const int* __restrict__ deg, int* __restrict__ offs,
                        int* __restrict__ bsum) {
  __shared__ int s[256];
  int t = threadIdx.x;
  int i = blockIdx.x * 256 + t;
  int v = (i < NN) ? deg[i] : 0;
  s[t] = v; __syncthreads();
  for (int off = 1; off < 256; off <<= 1) {
    int x = (t >= off) ? s[t - off] : 0;
    __syncthreads();
    s[t] += x;
    __syncthreads();
  }
  if (i < NN) offs[i] = s[t] - v;          // exclusive within block
  if (t == 255) bsum[blockIdx.x] = s[255]; // block total
}

__global__ void k_scan2(int* __restrict__ bsum, int nb) {
  __shared__ int s[512];
  int t = threadIdx.x;
  int v = (t < nb) ? bsum[t] : 0;
  s[t] = v; __syncthreads();
  for (int off = 1; off < 512; off <<= 1) {
    int x = (t >= off) ? s[t - off] : 0;
    __syncthreads();
    s[t] += x;
    __syncthreads();
  }
  if (t < nb) bsum[t] = s[t] - v;          // exclusive
}

__global__ void k_scan3(int* __restrict__ offs, const int* __restrict__ bsum) {
  int i = blockIdx.x * 256 + threadIdx.x;
  if (i < NN) offs[i] += bsum[i >> 8];
  else if (i == NN) offs[NN] = NE;
}

// single 8B packed scatter: (src, weight-bits) -> one line-dirtying store
__global__ void k_fill(const int* __restrict__ src, const int* __restrict__ dst,
                       const float* __restrict__ ef, int* __restrict__ cursor,
                       int2* __restrict__ epack) {
  int e = blockIdx.x * 256 + threadIdx.x;
  if (e >= NE) return;
  int d = dst[e];
  int p = atomicAdd(&cursor[d], 1);
  epack[p] = make_int2(src[e], __float_as_int(ef[e]));
}

// ---------------- lift: h16 = fp16(tanh(x @ Wl + bl)), thread per node ----------------
__global__ __launch_bounds__(256) void k_lift(const float* __restrict__ x,
                                              const float* __restrict__ Wl,
                                              const float* __restrict__ bl,
                                              unsigned short* __restrict__ h16) {
  int n = blockIdx.x * 256 + threadIdx.x;
  if (n >= NN) return;
  const float4* W4 = (const float4*)Wl;        // [16][25] float4
  const float4* b4 = (const float4*)bl;
  float4 acc[25];
  #pragma unroll
  for (int j = 0; j < 25; ++j) acc[j] = b4[j];
  const float4* xr = (const float4*)(x + (size_t)n * INF);
  for (int k4 = 0; k4 < 4; ++k4) {
    float4 xv = xr[k4];
    #pragma unroll
    for (int c = 0; c < 4; ++c) {
      float xs = (&xv.x)[c];
      int k = k4 * 4 + c;
      #pragma unroll
      for (int j = 0; j < 25; ++j) {
        acc[j].x = fmaf(xs, W4[k * 25 + j].x, acc[j].x);
        acc[j].y = fmaf(xs, W4[k * 25 + j].y, acc[j].y);
        acc[j].z = fmaf(xs, W4[k * 25 + j].z, acc[j].z);
        acc[j].w = fmaf(xs, W4[k * 25 + j].w, acc[j].w);
      }
    }
  }
  uint2* o = (uint2*)(h16 + (size_t)n * HID);
  #pragma unroll
  for (int j = 0; j < 25; ++j) {
    float4 v = acc[j];
    o[j] = make_uint2(pk_f16(tanhf(v.x), tanhf(v.y)),
                      pk_f16(tanhf(v.z), tanhf(v.w)));
  }
}

// -------- reduce: red[n][f] = sum over in-edges of h16[src][f]*w (fp32 acc) --------
// wave per node; lanes 0..24 each own 4 features (one uint2 = 4 fp16);
// edge loop unrolled x4 with independent 8B gathers in flight.
__global__ __launch_bounds__(256) void k_reduce(const unsigned short* __restrict__ h16,
                                                const int* __restrict__ offs,
                                                const int2* __restrict__ ep,
                                                float* __restrict__ red) {
  int wid = (blockIdx.x * 256 + threadIdx.x) >> 6;  // node (grid exact: 100k waves)
  int node = __builtin_amdgcn_readfirstlane(wid);
  int lane = threadIdx.x & 63;
  int lc = lane < 25 ? lane : 24;   // clamp: lanes 25..63 dup lane 24
  int beg = offs[node], end = offs[node + 1];
  const uint2* __restrict__ h2 = (const uint2*)h16;   // row = 25 uint2
  float4 acc = make_float4(0.f, 0.f, 0.f, 0.f);
  int i = beg;
  for (; i + 4 <= end; i += 4) {
    int2 e0 = ep[i + 0], e1 = ep[i + 1], e2 = ep[i + 2], e3 = ep[i + 3];
    uint2 v0 = h2[(size_t)e0.x * 25 + lc];
    uint2 v1 = h2[(size_t)e1.x * 25 + lc];
    uint2 v2 = h2[(size_t)e2.x * 25 + lc];
    uint2 v3 = h2[(size_t)e3.x * 25 + lc];
    float w0 = __int_as_float(e0.y), w1 = __int_as_float(e1.y);
    float w2 = __int_as_float(e2.y), w3 = __int_as_float(e3.y);
    float2 a0 = up_f16(v0.x), b0 = up_f16(v0.y);
    float2 a1 = up_f16(v1.x), b1 = up_f16(v1.y);
    float2 a2 = up_f16(v2.x), b2 = up_f16(v2.y);
    float2 a3 = up_f16(v3.x), b3 = up_f16(v3.y);
    acc.x = fmaf(w0, a0.x, acc.x); acc.y = fmaf(w0, a0.y, acc.y);
    acc.z = fmaf(w0, b0.x, acc.z); acc.w = fmaf(w0, b0.y, acc.w);
    acc.x = fmaf(w1, a1.x, acc.x); acc.y = fmaf(w1, a1.y, acc.y);
    acc.z = fmaf(w1, b1.x, acc.z); acc.w = fmaf(w1, b1.y, acc.w);
    acc.x = fmaf(w2, a2.x, acc.x); acc.y = fmaf(w2, a2.y, acc.y);
    acc.z = fmaf(w2, b2.x, acc.z); acc.w = fmaf(w2, b2.y, acc.w);
    acc.x = fmaf(w3, a3.x, acc.x); acc.y = fmaf(w3, a3.y, acc.y);
    acc.z = fmaf(w3, b3.x, acc.z); acc.w = fmaf(w3, b3.y, acc.w);
  }
  for (; i < end; ++i) {
    int2 e0 = ep[i];
    uint2 v0 = h2[(size_t)e0.x * 25 + lc];
    float w0 = __int_as_float(e0.y);
    float2 a0 = up_f16(v0.x), b0 = up_f16(v0.y);
    acc.x = fmaf(w0, a0.x, acc.x); acc.y = fmaf(w0, a0.y, acc.y);
    acc.z = fmaf(w0, b0.x, acc.z); acc.w = fmaf(w0, b0.y, acc.w);
  }
  if (lane < 25) ((float4*)red)[(size_t)node * 25 + lane] = acc;
}

// -------- mlp: out16 = fp16(relu(h16 @ W[0:100] + r @ W[100:200] + b)) --------
// Block = 256 threads = 4 waves = 64 nodes. Wave w computes output columns
// [25w, 25w+25) for all 64 nodes: acc[25] scalars/thread. Node rows staged in
// LDS fp32 (stride 101, conflict-free reads); W values are wave-uniform ->
// scalar loads. Results transposed through LDS, stored packed fp16.
__global__ __launch_bounds__(256) void k_mlp(const unsigned short* __restrict__ h16,
                                             const float* __restrict__ r,
                                             const float* __restrict__ W,
                                             const float* __restrict__ b,
                                             unsigned short* __restrict__ out16) {
  __shared__ float sh[64][101];
  const int t = threadIdx.x;
  const int w = __builtin_amdgcn_readfirstlane(t >> 6);  // wave id 0..3
  const int lane = t & 63;
  const size_t base  = (size_t)blockIdx.x * 6400;        // float index (r)
  const size_t base2 = (size_t)blockIdx.x * 3200;        // uint index (h16/out16)
  const size_t limit  = (size_t)NN * HID;                // 10,000,000
  const size_t limit2 = (size_t)NN * 50;                 // 5,000,000 uints
  const float* Wq = W + w * 25;

  float acc[25];
  #pragma unroll
  for (int j = 0; j < 25; ++j) acc[j] = b[w * 25 + j];

  // ---- phase 1: stage h16 rows (convert to fp32), accumulate vs W rows 0..99 ----
  const unsigned int* hp = (const unsigned int*)h16;
  #pragma unroll
  for (int i = 0; i < 13; ++i) {
    int f2 = i * 256 + t;                 // uint index within block [0,3200)
    if (f2 < 3200) {
      size_t g = base2 + f2;
      if (g >= limit2) g = limit2 - 1;
      float2 f = up_f16(hp[g]);
      int row = f2 / 50, c2 = (f2 % 50) * 2;
      sh[row][c2] = f.x;
      sh[row][c2 + 1] = f.y;
    }
  }
  __syncthreads();
  #pragma unroll 2
  for (int k = 0; k < 100; ++k) {
    float hv = sh[lane][k];
    const float* Wrow = Wq + (size_t)k * HID;
    #pragma unroll
    for (int j = 0; j < 25; ++j) acc[j] = fmaf(hv, Wrow[j], acc[j]);
  }
  __syncthreads();

  // ---- phase 2: stage r rows (fp32), accumulate vs W rows 100..199 ----
  #pragma unroll
  for (int i = 0; i < 25; ++i) {
    int flat = i * 256 + t;
    size_t g = base + flat;
    if (g >= limit) g = limit - 1;
    sh[flat / 100][flat % 100] = r[g];
  }
  __syncthreads();
  #pragma unroll 2
  for (int k = 0; k < 100; ++k) {
    float hv = sh[lane][k];
    const float* Wrow = Wq + (size_t)(HID + k) * HID;
    #pragma unroll
    for (int j = 0; j < 25; ++j) acc[j] = fmaf(hv, Wrow[j], acc[j]);
  }
  __syncthreads();

  // ---- relu + transpose through LDS, store packed fp16 ----
  #pragma unroll
  for (int j = 0; j < 25; ++j) sh[lane][w * 25 + j] = fmaxf(acc[j], 0.f);
  __syncthreads();
  unsigned int* op = (unsigned int*)out16;
  #pragma unroll
  for (int i = 0; i < 13; ++i) {
    int f2 = i * 256 + t;
    if (f2 < 3200) {
      size_t g = base2 + f2;
      if (g < limit2) {
        int row = f2 / 50, c2 = (f2 % 50) * 2;
        op[g] = pk_f16(sh[row][c2], sh[row][c2 + 1]);
      }
    }
  }
}

// -------- out: sigmoid(h16 @ Wo + bo), thread per node --------
__global__ __launch_bounds__(256) void k_out(const unsigned short* __restrict__ h16,
                                             const float* __restrict__ Wo,
                                             const float* __restrict__ bo,
                                             float* __restrict__ out) {
  int n = blockIdx.x * 256 + threadIdx.x;
  if (n >= NN) return;
  float a0 = bo[0], a1 = bo[1], a2 = bo[2];
  const uint2* hr = (const uint2*)(h16 + (size_t)n * HID);
  for (int k2 = 0; k2 < 25; ++k2) {
    uint2 v = hr[k2];
    float2 fa = up_f16(v.x), fb = up_f16(v.y);
    int k = k2 * 4;
    a0 = fmaf(fa.x, Wo[(k + 0) * 3 + 0], a0); a1 = fmaf(fa.x, Wo[(k + 0) * 3 + 1], a1); a2 = fmaf(fa.x, Wo[(k + 0) * 3 + 2], a2);
    a0 = fmaf(fa.y, Wo[(k + 1) * 3 + 0], a0); a1 = fmaf(fa.y, Wo[(k + 1) * 3 + 1], a1); a2 = fmaf(fa.y, Wo[(k + 1) * 3 + 2], a2);
    a0 = fmaf(fb.x, Wo[(k + 2) * 3 + 0], a0); a1 = fmaf(fb.x, Wo[(k + 2) * 3 + 1], a1); a2 = fmaf(fb.x, Wo[(k + 2) * 3 + 2], a2);
    a0 = fmaf(fb.y, Wo[(k + 3) * 3 + 0], a0); a1 = fmaf(fb.y, Wo[(k + 3) * 3 + 1], a1); a2 = fmaf(fb.y, Wo[(k + 3) * 3 + 2], a2);
  }
  out[(size_t)n * 3 + 0] = 1.f / (1.f + expf(-a0));
  out[(size_t)n * 3 + 1] = 1.f / (1.f + expf(-a1));
  out[(size_t)n * 3 + 2] = 1.f / (1.f + expf(-a2));
}

extern "C" void kernel_launch(void* const* d_in, const int* in_sizes, int n_in,
                              void* d_out, int out_size, void* d_ws, size_t ws_size,
                              hipStream_t stream) {
  const float* x  = (const float*)d_in[0];
  const float* ef = (const float*)d_in[1];
  const int*   src = (const int*)d_in[2];
  const int*   dst = (const int*)d_in[3];
  const float* Wl = (const float*)d_in[4];
  const float* bl = (const float*)d_in[5];
  const float* W1 = (const float*)d_in[6];
  const float* b1 = (const float*)d_in[7];
  const float* W2 = (const float*)d_in[8];
  const float* b2 = (const float*)d_in[9];
  const float* W3 = (const float*)d_in[10];
  const float* b3 = (const float*)d_in[11];
  const float* Wo = (const float*)d_in[12];
  const float* bo = (const float*)d_in[13];
  float* out = (float*)d_out;

  // workspace layout (~93.6 MB)
  char* ws = (char*)d_ws;
  float*          red    = (float*)(ws);                        // 40,000,000 B (fp32 reduce out)
  unsigned short* hA16   = (unsigned short*)(ws + 40000000);    // 20,000,000 B
  unsigned short* hB16   = (unsigned short*)(ws + 60000000);    // 20,000,000 B
  int*            offs   = (int*)(ws + 80000000);               // (NN+1)*4 -> pad 400,128
  int*            cursor = (int*)(ws + 80400128);               // NN*4 -> pad 400,128 (also deg)
  int2*           epack  = (int2*)(ws + 80800256);              // NE*8 = 12,800,000 B
  int*            bsum   = (int*)(ws + 93600256);               // 391*4

  const int scanBlocks = (NN + 255) / 256;          // 391
  const int mlpBlocks  = (NN + 63) / 64;            // 1563

  // ---- CSR build (deg lives in `cursor`) ----
  hipMemsetAsync(cursor, 0, NN * sizeof(int), stream);
  k_hist <<<(NE + 255) / 256, 256, 0, stream>>>(dst, cursor);
  k_scan1<<<scanBlocks, 256, 0, stream>>>(cursor, offs, bsum);
  k_scan2<<<1, 512, 0, stream>>>(bsum, scanBlocks);
  k_scan3<<<scanBlocks, 256, 0, stream>>>(offs, bsum);
  hipMemcpyAsync(cursor, offs, NN * sizeof(int), hipMemcpyDeviceToDevice, stream);
  k_fill <<<(NE + 255) / 256, 256, 0, stream>>>(src, dst, ef, cursor, epack);

  // ---- network ----
  k_lift<<<scanBlocks, 256, 0, stream>>>(x, Wl, bl, hA16);

  k_reduce<<<NN / 4, 256, 0, stream>>>(hA16, offs, epack, red);
  k_mlp   <<<mlpBlocks, 256, 0, stream>>>(hA16, red, W1, b1, hB16);

  k_reduce<<<NN / 4, 256, 0, stream>>>(hB16, offs, epack, red);
  k_mlp   <<<mlpBlocks, 256, 0, stream>>>(hB16, red, W2, b2, hA16);

  k_reduce<<<NN / 4, 256, 0, stream>>>(hA16, offs, epack, red);
  k_mlp   <<<mlpBlocks, 256, 0, stream>>>(hA16, red, W3, b3, hB16);

  k_out<<<scanBlocks, 256, 0, stream>>>(hB16, Wo, bo, out);
}